// Round 1
// baseline (80.975 us; speedup 1.0000x reference)
//
#include <hip/hip_runtime.h>
#include <math.h>

// Problem constants (fixed by reference):
//   B=4096 batch, IN_F=1024, NQ=4 qubits, L=2 layers, C=IN_F/NQ=256 circuits.
// One thread simulates one (b,c) 4-qubit circuit entirely in registers.
//
// Algebra used:
//  * RX(w0)*RX(x)|0> = RX(x+w0)|0>  -> embedding + layer-0 RX fused into one
//    product-state build: amp[n] = (-i)^popc(n) * prod_q (bit_q ? sin : cos)((x_q+w0_q)/2)
//  * CNOTs with compile-time ctrl/tgt on fully unrolled loops are pure
//    register renames (zero instructions after compilation).
//  * State index n = q0*8 + q1*4 + q2*2 + q3 (qubit q -> bit mask 8>>q),
//    matching the reference's tensordot axis order.

#define BQ 4096
#define CQ 256

__global__ __launch_bounds__(256) void qsim_kernel(
    const float* __restrict__ x,
    const float* __restrict__ w,
    float* __restrict__ out)
{
    const int tid = blockIdx.x * blockDim.x + threadIdx.x;   // [0, B*C)
    const int c = tid & (CQ - 1);

    // x[b, c*4 .. c*4+3] == flat float4 index tid  (coalesced 16B/lane)
    const float4 xv = reinterpret_cast<const float4*>(x)[tid];
    // weights (C, 2, 4): two float4 per circuit (L2-resident, 8KB total)
    const float4 w0 = reinterpret_cast<const float4*>(w)[c * 2 + 0];
    const float4 w1 = reinterpret_cast<const float4*>(w)[c * 2 + 1];

    // Fused embedding + layer-0 RX angles
    float cq[4], sq[4];
    __sincosf((xv.x + w0.x) * 0.5f, &sq[0], &cq[0]);
    __sincosf((xv.y + w0.y) * 0.5f, &sq[1], &cq[1]);
    __sincosf((xv.z + w0.z) * 0.5f, &sq[2], &cq[2]);
    __sincosf((xv.w + w0.w) * 0.5f, &sq[3], &cq[3]);

    // Layer-1 RX half-angle trig
    float c1[4], s1[4];
    __sincosf(w1.x * 0.5f, &s1[0], &c1[0]);
    __sincosf(w1.y * 0.5f, &s1[1], &c1[1]);
    __sincosf(w1.z * 0.5f, &s1[2], &c1[2]);
    __sincosf(w1.w * 0.5f, &s1[3], &c1[3]);

    // Build product state: amp[n] = (-i)^popc(n) * m(n)
    float ar[16], ai[16];
#pragma unroll
    for (int n = 0; n < 16; ++n) {
        const float m = ((n & 8) ? sq[0] : cq[0])
                      * ((n & 4) ? sq[1] : cq[1])
                      * ((n & 2) ? sq[2] : cq[2])
                      * ((n & 1) ? sq[3] : cq[3]);
        const int k = ((n & 1) + ((n >> 1) & 1) + ((n >> 2) & 1) + ((n >> 3) & 1)) & 3;
        ar[n] = (k == 0) ? m : ((k == 2) ? -m : 0.0f);
        ai[n] = (k == 1) ? -m : ((k == 3) ? m : 0.0f);
    }

    // ---- CNOT ring #1: CNOT(0,1), CNOT(1,2), CNOT(2,3), CNOT(3,0) ----
#pragma unroll
    for (int q = 0; q < 4; ++q) {
        const int cm = 8 >> q;
        const int tm = 8 >> ((q + 1) & 3);
#pragma unroll
        for (int n = 0; n < 16; ++n) {
            if ((n & cm) && !(n & tm)) {
                const int n1 = n | tm;
                float t;
                t = ar[n]; ar[n] = ar[n1]; ar[n1] = t;
                t = ai[n]; ai[n] = ai[n1]; ai[n1] = t;
            }
        }
    }

    // ---- Layer-1 RX on each wire ----
#pragma unroll
    for (int q = 0; q < 4; ++q) {
        const int m = 8 >> q;
        const float cg = c1[q], sg = s1[q];
#pragma unroll
        for (int n = 0; n < 16; ++n) {
            if (!(n & m)) {
                const int n1 = n | m;
                const float a_r = ar[n], a_i = ai[n];
                const float b_r = ar[n1], b_i = ai[n1];
                // a' = c*a - i*s*b ; b' = c*b - i*s*a
                ar[n]  = cg * a_r + sg * b_i;
                ai[n]  = cg * a_i - sg * b_r;
                ar[n1] = cg * b_r + sg * a_i;
                ai[n1] = cg * b_i - sg * a_r;
            }
        }
    }

    // ---- CNOT ring #2 ----
#pragma unroll
    for (int q = 0; q < 4; ++q) {
        const int cm = 8 >> q;
        const int tm = 8 >> ((q + 1) & 3);
#pragma unroll
        for (int n = 0; n < 16; ++n) {
            if ((n & cm) && !(n & tm)) {
                const int n1 = n | tm;
                float t;
                t = ar[n]; ar[n] = ar[n1]; ar[n1] = t;
                t = ai[n]; ai[n] = ai[n1]; ai[n1] = t;
            }
        }
    }

    // ---- Measure <Z_q> ----
    float p[16];
#pragma unroll
    for (int n = 0; n < 16; ++n) p[n] = ar[n] * ar[n] + ai[n] * ai[n];

    float z0 = 0.f, z1 = 0.f, z2 = 0.f, z3 = 0.f;
#pragma unroll
    for (int n = 0; n < 16; ++n) {
        z0 += (n & 8) ? -p[n] : p[n];
        z1 += (n & 4) ? -p[n] : p[n];
        z2 += (n & 2) ? -p[n] : p[n];
        z3 += (n & 1) ? -p[n] : p[n];
    }

    reinterpret_cast<float4*>(out)[tid] = make_float4(z0, z1, z2, z3);
}

extern "C" void kernel_launch(void* const* d_in, const int* in_sizes, int n_in,
                              void* d_out, int out_size, void* d_ws, size_t ws_size,
                              hipStream_t stream) {
    const float* x = (const float*)d_in[0];        // (4096, 1024) fp32
    const float* w = (const float*)d_in[1];        // (256, 2, 4) fp32
    float* out = (float*)d_out;                    // (4096, 1024) fp32

    const int total = BQ * CQ;                     // 1,048,576 threads
    qsim_kernel<<<total / 256, 256, 0, stream>>>(x, w, out);
}

// Round 2
// 80.776 us; speedup vs baseline: 1.0025x; 1.0025x over previous
//
#include <hip/hip_runtime.h>
#include <math.h>

// Problem constants (fixed by reference):
//   B=4096 batch, IN_F=1024, NQ=4 qubits, L=2 layers, C=IN_F/NQ=256 circuits.
// One thread simulates one (b,c) 4-qubit circuit entirely in registers.
//
// Algebra used:
//  * RX(w0)*RX(x)|0> = RX(x+w0)|0>  -> embedding + layer-0 RX fused into one
//    product-state build: amp[n] = (-i)^popc(n) * prod_q (bit_q ? sin : cos)((x_q+w0_q)/2)
//  * CNOTs with compile-time ctrl/tgt on fully unrolled loops are pure
//    register renames (zero instructions after compilation).
//  * State index n = q0*8 + q1*4 + q2*2 + q3 (qubit q -> bit mask 8>>q),
//    matching the reference's tensordot axis order.
//
// R1 change: __sincosf -> native __sinf/__cosf (v_sin_f32/v_cos_f32).
// __sincosf resolved to the precise ocml sincos (range-reduction branches +
// pointer out-params) and dominated runtime. Angles are small (|t| < ~5 rad),
// native trig error ~1e-6 << 1.98e-2 threshold.

#define BQ 4096
#define CQ 256

__global__ __launch_bounds__(256) void qsim_kernel(
    const float* __restrict__ x,
    const float* __restrict__ w,
    float* __restrict__ out)
{
    const int tid = blockIdx.x * blockDim.x + threadIdx.x;   // [0, B*C)
    const int c = tid & (CQ - 1);

    // x[b, c*4 .. c*4+3] == flat float4 index tid  (coalesced 16B/lane)
    const float4 xv = reinterpret_cast<const float4*>(x)[tid];
    // weights (C, 2, 4): two float4 per circuit (L2-resident, 8KB total)
    const float4 w0 = reinterpret_cast<const float4*>(w)[c * 2 + 0];
    const float4 w1 = reinterpret_cast<const float4*>(w)[c * 2 + 1];

    // Fused embedding + layer-0 RX half-angles
    float t0 = (xv.x + w0.x) * 0.5f;
    float t1 = (xv.y + w0.y) * 0.5f;
    float t2 = (xv.z + w0.z) * 0.5f;
    float t3 = (xv.w + w0.w) * 0.5f;
    float cq[4], sq[4];
    sq[0] = __sinf(t0); cq[0] = __cosf(t0);
    sq[1] = __sinf(t1); cq[1] = __cosf(t1);
    sq[2] = __sinf(t2); cq[2] = __cosf(t2);
    sq[3] = __sinf(t3); cq[3] = __cosf(t3);

    // Layer-1 RX half-angle trig
    float u0 = w1.x * 0.5f, u1 = w1.y * 0.5f, u2 = w1.z * 0.5f, u3 = w1.w * 0.5f;
    float c1[4], s1[4];
    s1[0] = __sinf(u0); c1[0] = __cosf(u0);
    s1[1] = __sinf(u1); c1[1] = __cosf(u1);
    s1[2] = __sinf(u2); c1[2] = __cosf(u2);
    s1[3] = __sinf(u3); c1[3] = __cosf(u3);

    // Build product state: amp[n] = (-i)^popc(n) * m(n)
    float ar[16], ai[16];
#pragma unroll
    for (int n = 0; n < 16; ++n) {
        const float m = ((n & 8) ? sq[0] : cq[0])
                      * ((n & 4) ? sq[1] : cq[1])
                      * ((n & 2) ? sq[2] : cq[2])
                      * ((n & 1) ? sq[3] : cq[3]);
        const int k = ((n & 1) + ((n >> 1) & 1) + ((n >> 2) & 1) + ((n >> 3) & 1)) & 3;
        ar[n] = (k == 0) ? m : ((k == 2) ? -m : 0.0f);
        ai[n] = (k == 1) ? -m : ((k == 3) ? m : 0.0f);
    }

    // ---- CNOT ring #1: CNOT(0,1), CNOT(1,2), CNOT(2,3), CNOT(3,0) ----
#pragma unroll
    for (int q = 0; q < 4; ++q) {
        const int cm = 8 >> q;
        const int tm = 8 >> ((q + 1) & 3);
#pragma unroll
        for (int n = 0; n < 16; ++n) {
            if ((n & cm) && !(n & tm)) {
                const int n1 = n | tm;
                float t;
                t = ar[n]; ar[n] = ar[n1]; ar[n1] = t;
                t = ai[n]; ai[n] = ai[n1]; ai[n1] = t;
            }
        }
    }

    // ---- Layer-1 RX on each wire ----
#pragma unroll
    for (int q = 0; q < 4; ++q) {
        const int m = 8 >> q;
        const float cg = c1[q], sg = s1[q];
#pragma unroll
        for (int n = 0; n < 16; ++n) {
            if (!(n & m)) {
                const int n1 = n | m;
                const float a_r = ar[n], a_i = ai[n];
                const float b_r = ar[n1], b_i = ai[n1];
                // a' = c*a - i*s*b ; b' = c*b - i*s*a
                ar[n]  = cg * a_r + sg * b_i;
                ai[n]  = cg * a_i - sg * b_r;
                ar[n1] = cg * b_r + sg * a_i;
                ai[n1] = cg * b_i - sg * a_r;
            }
        }
    }

    // ---- CNOT ring #2 ----
#pragma unroll
    for (int q = 0; q < 4; ++q) {
        const int cm = 8 >> q;
        const int tm = 8 >> ((q + 1) & 3);
#pragma unroll
        for (int n = 0; n < 16; ++n) {
            if ((n & cm) && !(n & tm)) {
                const int n1 = n | tm;
                float t;
                t = ar[n]; ar[n] = ar[n1]; ar[n1] = t;
                t = ai[n]; ai[n] = ai[n1]; ai[n1] = t;
            }
        }
    }

    // ---- Measure <Z_q> ----
    float p[16];
#pragma unroll
    for (int n = 0; n < 16; ++n) p[n] = ar[n] * ar[n] + ai[n] * ai[n];

    float z0 = 0.f, z1 = 0.f, z2 = 0.f, z3 = 0.f;
#pragma unroll
    for (int n = 0; n < 16; ++n) {
        z0 += (n & 8) ? -p[n] : p[n];
        z1 += (n & 4) ? -p[n] : p[n];
        z2 += (n & 2) ? -p[n] : p[n];
        z3 += (n & 1) ? -p[n] : p[n];
    }

    reinterpret_cast<float4*>(out)[tid] = make_float4(z0, z1, z2, z3);
}

extern "C" void kernel_launch(void* const* d_in, const int* in_sizes, int n_in,
                              void* d_out, int out_size, void* d_ws, size_t ws_size,
                              hipStream_t stream) {
    const float* x = (const float*)d_in[0];        // (4096, 1024) fp32
    const float* w = (const float*)d_in[1];        // (256, 2, 4) fp32
    float* out = (float*)d_out;                    // (4096, 1024) fp32

    const int total = BQ * CQ;                     // 1,048,576 threads
    qsim_kernel<<<total / 256, 256, 0, stream>>>(x, w, out);
}

// Round 3
// 77.008 us; speedup vs baseline: 1.0515x; 1.0489x over previous
//
#include <hip/hip_runtime.h>
#include <math.h>

// B=4096, IN_F=1024, NQ=4, L=2, C=256. One thread = one (b,c) 4-qubit sim.
//
// R3 restructure (algebra, all verified against hand-simulated basis states):
//  * Embedding + layer-0 RX fused: RX(w0)RX(x)|0> = RX(x+w0)|0>.
//  * CNOT ring #1 folded into init as compile-time permutation s[n]
//    (amp_after[n] = amp_before[s[n]]), phase phi1[n] = (-popc(s[n])) mod 4.
//  * State kept as i^phi * real as long as possible; RX gates applied in
//    order q3,q0,q1,q2 (they commute). Init amps have one nonzero component
//    (literal zeros in source) -> compiler constant-folds q3 to 16 FMA and
//    q0 to 32 mul; only q1,q2 are full complex (64 ops each).
//  * CNOT ring #2 folded into measurement: z_q = sum (-1)^popc(n&K_q) p[n],
//    K = {7,12,14,15}; computed via a shared Walsh butterfly (38 adds).
//  * Native trig (v_sin_f32/v_cos_f32); angles are small, err ~1e-6.

#define BQ 4096
#define CQ 256

__global__ __launch_bounds__(256) void qsim_kernel(
    const float* __restrict__ x,
    const float* __restrict__ w,
    float* __restrict__ out)
{
    const int tid = blockIdx.x * blockDim.x + threadIdx.x;   // [0, B*C)
    const int c = tid & (CQ - 1);

    const float4 xv = reinterpret_cast<const float4*>(x)[tid];      // coalesced 16B
    const float4 w0 = reinterpret_cast<const float4*>(w)[c * 2 + 0];
    const float4 w1 = reinterpret_cast<const float4*>(w)[c * 2 + 1];

    // Fused embedding + layer-0 RX half-angles
    const float t0 = (xv.x + w0.x) * 0.5f;
    const float t1 = (xv.y + w0.y) * 0.5f;
    const float t2 = (xv.z + w0.z) * 0.5f;
    const float t3 = (xv.w + w0.w) * 0.5f;
    const float cA = __cosf(t0), sA = __sinf(t0);
    const float cB = __cosf(t1), sB = __sinf(t1);
    const float cC = __cosf(t2), sC = __sinf(t2);
    const float cD = __cosf(t3), sD = __sinf(t3);

    // Layer-1 RX half-angle trig (per-qubit gate coefficients)
    float gc[4], gs[4];
    gc[0] = __cosf(w1.x * 0.5f); gs[0] = __sinf(w1.x * 0.5f);
    gc[1] = __cosf(w1.y * 0.5f); gs[1] = __sinf(w1.y * 0.5f);
    gc[2] = __cosf(w1.z * 0.5f); gs[2] = __sinf(w1.z * 0.5f);
    gc[3] = __cosf(w1.w * 0.5f); gs[3] = __sinf(w1.w * 0.5f);

    // Product-state magnitudes via pairwise products: m[n], n = b0b1b2b3
    float a01[4], a23[4];
    a01[0] = cA * cB; a01[1] = cA * sB; a01[2] = sA * cB; a01[3] = sA * sB;
    a23[0] = cC * cD; a23[1] = cC * sD; a23[2] = sC * cD; a23[3] = sC * sD;

    float m[16];
#pragma unroll
    for (int n = 0; n < 16; ++n) m[n] = a01[n >> 2] * a23[n & 3];

    // CNOT ring #1 folded: r[n] = m[s[n]], phase phi1[n] = (-popc(s[n])) & 3
    constexpr int sp[16]   = {0,13,3,14,6,11,5,8,12,1,15,2,10,7,9,4};
    constexpr int phi1[16] = {0,1, 2,1, 2,1, 2,3, 2, 3,0, 3,2, 1,2,3};

    float ar[16], ai[16];
#pragma unroll
    for (int n = 0; n < 16; ++n) {
        const float r = m[sp[n]];
        ar[n] = (phi1[n] == 0) ? r : ((phi1[n] == 2) ? -r : 0.0f);
        ai[n] = (phi1[n] == 1) ? r : ((phi1[n] == 3) ? -r : 0.0f);
    }

    // Layer-1 RX gates, order q3,q0,q1,q2 (masks 1,8,4,2) for max zero-folding.
    constexpr int gq[4]  = {3, 0, 1, 2};
    constexpr int gm[4]  = {1, 8, 4, 2};
#pragma unroll
    for (int g = 0; g < 4; ++g) {
        const float cg = gc[gq[g]], sg = gs[gq[g]];
        const int mk = gm[g];
#pragma unroll
        for (int n = 0; n < 16; ++n) {
            if (!(n & mk)) {
                const int n1 = n | mk;
                const float r0 = ar[n],  i0 = ai[n];
                const float r1 = ar[n1], i1 = ai[n1];
                // a' = c*a - i*s*b ; b' = c*b - i*s*a
                ar[n]  = cg * r0 + sg * i1;
                ai[n]  = cg * i0 - sg * r1;
                ar[n1] = cg * r1 + sg * i0;
                ai[n1] = cg * i1 - sg * r0;
            }
        }
    }

    // Probabilities
    float p[16];
#pragma unroll
    for (int n = 0; n < 16; ++n) p[n] = ar[n] * ar[n] + ai[n] * ai[n];

    // CNOT ring #2 folded into measurement: z_q = sum (-1)^popc(n&K_q) p[n],
    // K0=7, K1=12, K2=14, K3=15. Shared Walsh butterfly:
    float sAv[8], dAv[8];
#pragma unroll
    for (int k = 0; k < 8; ++k) {
        sAv[k] = p[2 * k] + p[2 * k + 1];
        dAv[k] = p[2 * k] - p[2 * k + 1];
    }
    float dd[4], ss[4], sd[4];
#pragma unroll
    for (int j = 0; j < 4; ++j) {
        dd[j] = dAv[2 * j] - dAv[2 * j + 1];   // for z0 (K=7) and z3 (K=15)
        ss[j] = sAv[2 * j] + sAv[2 * j + 1];   // for z1 (K=12)
        sd[j] = sAv[2 * j] - sAv[2 * j + 1];   // for z2 (K=14)
    }
    const float g0 = dd[0] - dd[1], g1 = dd[2] - dd[3];
    const float u0 = ss[0] - ss[1], u1 = ss[2] - ss[3];
    const float v0 = sd[0] - sd[1], v1 = sd[2] - sd[3];

    const float z0 = g0 + g1;
    const float z3 = g0 - g1;
    const float z1 = u0 - u1;
    const float z2 = v0 - v1;

    reinterpret_cast<float4*>(out)[tid] = make_float4(z0, z1, z2, z3);
}

extern "C" void kernel_launch(void* const* d_in, const int* in_sizes, int n_in,
                              void* d_out, int out_size, void* d_ws, size_t ws_size,
                              hipStream_t stream) {
    const float* x = (const float*)d_in[0];        // (4096, 1024) fp32
    const float* w = (const float*)d_in[1];        // (256, 2, 4) fp32
    float* out = (float*)d_out;                    // (4096, 1024) fp32

    const int total = BQ * CQ;                     // 1,048,576 threads
    qsim_kernel<<<total / 256, 256, 0, stream>>>(x, w, out);
}